// Round 9
// baseline (21.201 us; speedup 1.0000x reference)
//
#include <hip/hip_runtime.h>

// BoxCrossAttention: softmax over a length-1 key axis == 1.0, so
// out[b,c,w,h] = 9 * (vp[b] @ Wo + bo)[c],  vp = (mish(y@W1+b1)@W2+b2)[:,512:] @ Wv + bv.
// x / conv / unfold / q / k projections are dead code.
//
// R4: global spin-sync mega-kernel = 439us — dead (XCD fence/poll storm).
// R5: M9=Wv@Wo fold = 29.7us — 33M MACs, 8x live network. Dead.
// R6: 3-node chain = 19.9us. 2-node variants dead by arithmetic.
// R7: micro-opts neutral -> overhead-bound.
// R8: K2 contracts vp-partial against Wo (o9part); K1 spare block does cvec;
//     K3 = {32 L2 loads + shfl reduce + nontemporal broadcast write}.
//     (fix: nontemporal builtin needs a native ext_vector type, not HIP float4)

typedef float floatx4 __attribute__((ext_vector_type(4)));

__device__ __forceinline__ float mishf(float v) {
    float sp = (v > 20.0f) ? v : log1pf(expf(v));
    return v * tanhf(sp);
}

// K1: blocks 0..255: hidden[b][j] = mish(b1[j] + sum_t y[b][t]*W1[t][j])
//     block 256:     cvec[c] = 9*(bo[c] + sum_d bv[d]*Wo[d][c])
__global__ __launch_bounds__(256) void k1_hidden_cvec(const float* __restrict__ y,
                                                      const float* __restrict__ W1,
                                                      const float* __restrict__ b1,
                                                      const float* __restrict__ bv,
                                                      const float* __restrict__ Wo,
                                                      const float* __restrict__ bo,
                                                      float* __restrict__ hidden,
                                                      float* __restrict__ cvec) {
    int t = threadIdx.x;
    __shared__ float s_in[256];
    __shared__ float ps[256];
    if (blockIdx.x < 256) {
        int b  = blockIdx.x >> 6;
        int j0 = (blockIdx.x & 63) * 16;
        int col = j0 + (t & 15);
        int kc  = t >> 4;                        // 0..15, 16 rows each
        s_in[t] = y[b * 256 + t];
        __syncthreads();
        const float* w  = W1 + (size_t)(kc * 16) * 1024 + col;
        const float* ys = s_in + kc * 16;
        float a0 = 0, a1 = 0, a2 = 0, a3 = 0;
        #pragma unroll
        for (int r = 0; r < 16; r += 4) {
            a0 = fmaf(ys[r + 0], w[(r + 0) * 1024], a0);
            a1 = fmaf(ys[r + 1], w[(r + 1) * 1024], a1);
            a2 = fmaf(ys[r + 2], w[(r + 2) * 1024], a2);
            a3 = fmaf(ys[r + 3], w[(r + 3) * 1024], a3);
        }
        ps[t] = (a0 + a1) + (a2 + a3);
        __syncthreads();
        if (t < 16) {
            float s = 0;
            #pragma unroll
            for (int k = 0; k < 16; ++k) s += ps[t + 16 * k];
            hidden[b * 1024 + j0 + t] = mishf(s + b1[j0 + t]);
        }
    } else {
        s_in[t] = bv[t];
        __syncthreads();
        const float* w = Wo + t;                 // column c = t, coalesced
        float a0 = 0, a1 = 0, a2 = 0, a3 = 0;
        #pragma unroll 4
        for (int d = 0; d < 256; d += 4) {
            a0 = fmaf(s_in[d + 0], w[(d + 0) * 256], a0);
            a1 = fmaf(s_in[d + 1], w[(d + 1) * 256], a1);
            a2 = fmaf(s_in[d + 2], w[(d + 2) * 256], a2);
            a3 = fmaf(s_in[d + 3], w[(d + 3) * 256], a3);
        }
        cvec[t] = 9.0f * (((a0 + a1) + (a2 + a3)) + bo[t]);
    }
}

// K2: per block (b, 16 v_raw cols): v_raw slice -> vp partial (outer product)
//     -> o9part[blockIdx][c] = 9 * (part . Wo[:,c]).  grid 128.
__global__ __launch_bounds__(256) void k2_vraw_o9part(const float* __restrict__ hidden,
                                                      const float* __restrict__ W2,
                                                      const float* __restrict__ b2,
                                                      const float* __restrict__ Wv,
                                                      const float* __restrict__ Wo,
                                                      float* __restrict__ o9part) {
    int b  = blockIdx.x >> 5;
    int c0 = (blockIdx.x & 31) * 16;
    int t  = threadIdx.x;
    int col = c0 + (t & 15);
    int kc  = t >> 4;
    __shared__ float4 h4_s[256];                 // 1024 floats
    __shared__ float ps[256];
    __shared__ float vr16[16];
    h4_s[t] = ((const float4*)(hidden + b * 1024))[t];
    __syncthreads();
    const float* h_s = (const float*)h4_s;
    const float* w  = W2 + (size_t)(kc * 64) * 1024 + 512 + col;
    const float* hs = h_s + kc * 64;
    float a0 = 0, a1 = 0, a2 = 0, a3 = 0;
    for (int r = 0; r < 64; r += 4) {
        a0 = fmaf(hs[r + 0], w[(size_t)(r + 0) * 1024], a0);
        a1 = fmaf(hs[r + 1], w[(size_t)(r + 1) * 1024], a1);
        a2 = fmaf(hs[r + 2], w[(size_t)(r + 2) * 1024], a2);
        a3 = fmaf(hs[r + 3], w[(size_t)(r + 3) * 1024], a3);
    }
    ps[t] = (a0 + a1) + (a2 + a3);
    __syncthreads();
    if (t < 16) {
        float s = 0;
        #pragma unroll
        for (int k = 0; k < 16; ++k) s += ps[t + 16 * k];
        vr16[t] = s + b2[512 + c0 + t];
    }
    __syncthreads();
    // vp partial: part[t] = sum_{k<16} vr16[k] * Wv[c0+k][t]  (coalesced in t)
    const float* wv = Wv + (size_t)c0 * 256 + t;
    float acc0 = 0, acc1 = 0;
    #pragma unroll
    for (int k = 0; k < 16; k += 2) {
        acc0 = fmaf(vr16[k],     wv[(k + 0) * 256], acc0);
        acc1 = fmaf(vr16[k + 1], wv[(k + 1) * 256], acc1);
    }
    ps[t] = acc0 + acc1;                         // reuse ps as part[256]
    __syncthreads();
    // o9part[c=t] = 9 * sum_d part[d] * Wo[d][t]  (Wo coalesced in t)
    const float* wo = Wo + t;
    float o0 = 0, o1 = 0, o2 = 0, o3 = 0;
    #pragma unroll 4
    for (int d = 0; d < 256; d += 4) {
        o0 = fmaf(ps[d + 0], wo[(d + 0) * 256], o0);
        o1 = fmaf(ps[d + 1], wo[(d + 1) * 256], o1);
        o2 = fmaf(ps[d + 2], wo[(d + 2) * 256], o2);
        o3 = fmaf(ps[d + 3], wo[(d + 3) * 256], o3);
    }
    o9part[(size_t)blockIdx.x * 256 + t] = 9.0f * ((o0 + o1) + (o2 + o3));
}

// K3: block (b,c): o9 = cvec[c] + sum_{p<32} o9part[b*32+p][c]; broadcast 4096
// slots with nontemporal ext-vector stores. grid 1024.
__global__ __launch_bounds__(256) void k3_bcast(const float* __restrict__ o9part,
                                                const float* __restrict__ cvec,
                                                floatx4* __restrict__ out) {
    int b = blockIdx.x >> 8, c = blockIdx.x & 255, t = threadIdx.x;
    // 8-way replicated load of the 32 partials (L2-resident), shfl reduce
    float v = o9part[(size_t)(b * 32 + (t & 31)) * 256 + c];
    v += __shfl_xor(v, 16);
    v += __shfl_xor(v, 8);
    v += __shfl_xor(v, 4);
    v += __shfl_xor(v, 2);
    v += __shfl_xor(v, 1);
    v += cvec[c];
    floatx4 vv = {v, v, v, v};
    floatx4* p = out + (size_t)blockIdx.x * 1024;
    __builtin_nontemporal_store(vv, &p[t]);
    __builtin_nontemporal_store(vv, &p[t + 256]);
    __builtin_nontemporal_store(vv, &p[t + 512]);
    __builtin_nontemporal_store(vv, &p[t + 768]);
}

// ---------------- fallback (proven round-2 kernels, 28KB ws) ----------------
__global__ __launch_bounds__(256) void k_hidden_fb(const float* __restrict__ y,
                                                   const float* __restrict__ W1,
                                                   const float* __restrict__ b1,
                                                   float* __restrict__ hidden) {
    int b  = blockIdx.x >> 4;
    int j0 = (blockIdx.x & 15) * 64;
    int t  = threadIdx.x;
    int col = j0 + (t & 63);
    int kc  = t >> 6;
    __shared__ float y_s[256];
    __shared__ float ps[256];
    y_s[t] = y[b * 256 + t];
    __syncthreads();
    const float* w  = W1 + (size_t)(kc * 64) * 1024 + col;
    const float* ys = y_s + kc * 64;
    float a0 = 0, a1 = 0, a2 = 0, a3 = 0;
    for (int r = 0; r < 64; r += 4) {
        a0 = fmaf(ys[r + 0], w[(r + 0) * 1024], a0);
        a1 = fmaf(ys[r + 1], w[(r + 1) * 1024], a1);
        a2 = fmaf(ys[r + 2], w[(r + 2) * 1024], a2);
        a3 = fmaf(ys[r + 3], w[(r + 3) * 1024], a3);
    }
    ps[t] = (a0 + a1) + (a2 + a3);
    __syncthreads();
    if (t < 64)
        hidden[b * 1024 + j0 + t] =
            mishf((ps[t] + ps[t + 64]) + (ps[t + 128] + ps[t + 192]) + b1[j0 + t]);
}

__global__ __launch_bounds__(256) void k_vraw_fb(const float* __restrict__ hidden,
                                                 const float* __restrict__ W2,
                                                 const float* __restrict__ b2,
                                                 float* __restrict__ v_raw) {
    int b  = blockIdx.x >> 5;
    int c0 = (blockIdx.x & 31) * 16;
    int t  = threadIdx.x;
    int col = c0 + (t & 15);
    int kc  = t >> 4;
    __shared__ float h_s[1024];
    __shared__ float ps[256];
    h_s[t]       = hidden[b * 1024 + t];
    h_s[t + 256] = hidden[b * 1024 + t + 256];
    h_s[t + 512] = hidden[b * 1024 + t + 512];
    h_s[t + 768] = hidden[b * 1024 + t + 768];
    __syncthreads();
    const float* w  = W2 + (size_t)(kc * 64) * 1024 + 512 + col;
    const float* hs = h_s + kc * 64;
    float a0 = 0, a1 = 0, a2 = 0, a3 = 0;
    for (int r = 0; r < 64; r += 4) {
        a0 = fmaf(hs[r + 0], w[(size_t)(r + 0) * 1024], a0);
        a1 = fmaf(hs[r + 1], w[(size_t)(r + 1) * 1024], a1);
        a2 = fmaf(hs[r + 2], w[(size_t)(r + 2) * 1024], a2);
        a3 = fmaf(hs[r + 3], w[(size_t)(r + 3) * 1024], a3);
    }
    ps[t] = (a0 + a1) + (a2 + a3);
    __syncthreads();
    if (t < 16) {
        float s = 0;
        #pragma unroll
        for (int k = 0; k < 16; ++k) s += ps[t + 16 * k];
        v_raw[b * 512 + c0 + t] = s + b2[512 + c0 + t];
    }
}

__global__ __launch_bounds__(256) void k_vp_fb(const float* __restrict__ v_raw,
                                               const float* __restrict__ Wv,
                                               const float* __restrict__ bv,
                                               float* __restrict__ vp) {
    int b  = blockIdx.x >> 3;
    int d0 = (blockIdx.x & 7) * 32;
    int t  = threadIdx.x;
    int col = d0 + (t & 31), kc = t >> 5;
    __shared__ float v_s[512];
    __shared__ float ps[256];
    v_s[t]       = v_raw[b * 512 + t];
    v_s[t + 256] = v_raw[b * 512 + t + 256];
    __syncthreads();
    const float* w  = Wv + (size_t)(kc * 64) * 256 + col;
    const float* vs = v_s + kc * 64;
    float a0 = 0, a1 = 0, a2 = 0, a3 = 0;
    for (int r = 0; r < 64; r += 4) {
        a0 = fmaf(vs[r + 0], w[(r + 0) * 256], a0);
        a1 = fmaf(vs[r + 1], w[(r + 1) * 256], a1);
        a2 = fmaf(vs[r + 2], w[(r + 2) * 256], a2);
        a3 = fmaf(vs[r + 3], w[(r + 3) * 256], a3);
    }
    ps[t] = (a0 + a1) + (a2 + a3);
    __syncthreads();
    if (t < 32) {
        float s = 0;
        #pragma unroll
        for (int k = 0; k < 8; ++k) s += ps[t + 32 * k];
        vp[b * 256 + d0 + t] = s + bv[d0 + t];
    }
}

__global__ __launch_bounds__(256) void k_out_fb(const float* __restrict__ vp,
                                                const float* __restrict__ Wo,
                                                const float* __restrict__ bo,
                                                float4* __restrict__ out) {
    int b = blockIdx.x >> 8, c = blockIdx.x & 255, t = threadIdx.x;
    __shared__ float red[256];
    red[t] = vp[b * 256 + t] * Wo[(size_t)t * 256 + c];
    __syncthreads();
    if (t < 64) {
        float s = (red[t] + red[t + 64]) + (red[t + 128] + red[t + 192]);
        s += __shfl_down(s, 32);
        s += __shfl_down(s, 16);
        s += __shfl_down(s, 8);
        s += __shfl_down(s, 4);
        s += __shfl_down(s, 2);
        s += __shfl_down(s, 1);
        if (t == 0) red[0] = 9.0f * (s + bo[c]);
    }
    __syncthreads();
    float v = red[0];
    float4 vv = make_float4(v, v, v, v);
    float4* p = out + (size_t)blockIdx.x * 1024;
    p[t]       = vv;
    p[t + 256] = vv;
    p[t + 512] = vv;
    p[t + 768] = vv;
}

extern "C" void kernel_launch(void* const* d_in, const int* in_sizes, int n_in,
                              void* d_out, int out_size, void* d_ws, size_t ws_size,
                              hipStream_t stream) {
    // 0:x 1:y 2:Wp 3:bp 4:W1 5:b1 6:W2 7:b2 8:Wq 9:bq 10:Wk 11:bk 12:Wv 13:bv 14:Wo 15:bo
    const float* y  = (const float*)d_in[1];
    const float* W1 = (const float*)d_in[4];
    const float* b1 = (const float*)d_in[5];
    const float* W2 = (const float*)d_in[6];
    const float* b2 = (const float*)d_in[7];
    const float* Wv = (const float*)d_in[12];
    const float* bv = (const float*)d_in[13];
    const float* Wo = (const float*)d_in[14];
    const float* bo = (const float*)d_in[15];

    float* ws     = (float*)d_ws;
    float* hidden = ws;                    // 4096 floats
    float* o9part = ws + 4096;             // 128 x 256 = 32768 floats
    float* cvec   = ws + 4096 + 32768;     // 256 floats
    const size_t need = (size_t)(4096 + 32768 + 256) * 4;   // ~148KB

    if (ws_size >= need) {
        k1_hidden_cvec<<<257,  256, 0, stream>>>(y, W1, b1, bv, Wo, bo, hidden, cvec);
        k2_vraw_o9part<<<128,  256, 0, stream>>>(hidden, W2, b2, Wv, Wo, o9part);
        k3_bcast      <<<1024, 256, 0, stream>>>(o9part, cvec, (floatx4*)d_out);
    } else {
        float* v_raw = ws + 4096;  // 2048
        float* vp    = ws + 6144;  // 1024
        k_hidden_fb<<<64,   256, 0, stream>>>(y, W1, b1, hidden);
        k_vraw_fb  <<<128,  256, 0, stream>>>(hidden, W2, b2, v_raw);
        k_vp_fb    <<<32,   256, 0, stream>>>(v_raw, Wv, bv, vp);
        k_out_fb   <<<1024, 256, 0, stream>>>(vp, Wo, bo, (float4*)d_out);
    }
}

// Round 10
// 19.978 us; speedup vs baseline: 1.0612x; 1.0612x over previous
//
#include <hip/hip_runtime.h>

// BoxCrossAttention: softmax over a length-1 key axis == 1.0, so
// out[b,c,w,h] = 9 * (vp[b] @ Wo + bo)[c],  vp = (mish(y@W1+b1)@W2+b2)[:,512:] @ Wv + bv.
// x / conv / unfold / q / k projections are dead code.
//
// Session ledger:
//   R2: 4-node split-K GEMV chain            = 21.0us
//   R4: 1-node global spin-sync              = 439us  (XCD fence/poll storm — dead)
//   R5: M9=Wv@Wo fold                        = 29.7us (33M MACs = 8x live network — dead)
//   R6: 3-node {hidden}{v_raw+vp_part}{out}  = 19.9us  <-- BEST (this file)
//   R7: micro-opts (K1 width, f4 staging, butterfly) = 20.05us (neutral)
//   R8/R9: K2 Wo-contraction + nontemporal K3 = 21.2us (hurt: K2 serial tail,
//          K3 33MB replicated L2 prologue)
// Conclusion: interiors are off the critical path; ~20us = 3-node dispatch
// floor + 16.8MB write floor + small-GEMV latency. 2-node variants dead by
// arithmetic (single-CU weight streaming ~44us; redundant W2 ~256MB L2).

__device__ __forceinline__ float mishf(float v) {
    float sp = (v > 20.0f) ? v : log1pf(expf(v));
    return v * tanhf(sp);
}

// K1: hidden[b][j] = mish(b1[j] + sum_t y[b][t]*W1[t][j]); grid 64
__global__ __launch_bounds__(256) void k_hidden(const float* __restrict__ y,
                                                const float* __restrict__ W1,
                                                const float* __restrict__ b1,
                                                float* __restrict__ hidden) {
    int b  = blockIdx.x >> 4;
    int j0 = (blockIdx.x & 15) * 64;
    int t  = threadIdx.x;
    int col = j0 + (t & 63);
    int kc  = t >> 6;
    __shared__ float y_s[256];
    __shared__ float ps[256];
    y_s[t] = y[b * 256 + t];
    __syncthreads();
    const float* w  = W1 + (size_t)(kc * 64) * 1024 + col;
    const float* ys = y_s + kc * 64;
    float a0 = 0, a1 = 0, a2 = 0, a3 = 0;
    for (int r = 0; r < 64; r += 4) {
        a0 = fmaf(ys[r + 0], w[(r + 0) * 1024], a0);
        a1 = fmaf(ys[r + 1], w[(r + 1) * 1024], a1);
        a2 = fmaf(ys[r + 2], w[(r + 2) * 1024], a2);
        a3 = fmaf(ys[r + 3], w[(r + 3) * 1024], a3);
    }
    ps[t] = (a0 + a1) + (a2 + a3);
    __syncthreads();
    if (t < 64)
        hidden[b * 1024 + j0 + t] =
            mishf((ps[t] + ps[t + 64]) + (ps[t + 128] + ps[t + 192]) + b1[j0 + t]);
}

// K2: v_raw[b][c] for 16 cols, then this block's vp partial:
// vp_part[blockIdx][d] = sum_{k<16} v_raw[b][c0+k] * Wv[c0+k][d].  grid 128.
__global__ __launch_bounds__(256) void k_vraw_vppart(const float* __restrict__ hidden,
                                                     const float* __restrict__ W2,
                                                     const float* __restrict__ b2,
                                                     const float* __restrict__ Wv,
                                                     float* __restrict__ vp_part) {
    int b  = blockIdx.x >> 5;
    int c0 = (blockIdx.x & 31) * 16;
    int t  = threadIdx.x;
    int col = c0 + (t & 15);
    int kc  = t >> 4;
    __shared__ float h_s[1024];
    __shared__ float ps[256];
    __shared__ float vr16[16];
    h_s[t]       = hidden[b * 1024 + t];
    h_s[t + 256] = hidden[b * 1024 + t + 256];
    h_s[t + 512] = hidden[b * 1024 + t + 512];
    h_s[t + 768] = hidden[b * 1024 + t + 768];
    __syncthreads();
    const float* w  = W2 + (size_t)(kc * 64) * 1024 + 512 + col;
    const float* hs = h_s + kc * 64;
    float a0 = 0, a1 = 0, a2 = 0, a3 = 0;
    for (int r = 0; r < 64; r += 4) {
        a0 = fmaf(hs[r + 0], w[(size_t)(r + 0) * 1024], a0);
        a1 = fmaf(hs[r + 1], w[(size_t)(r + 1) * 1024], a1);
        a2 = fmaf(hs[r + 2], w[(size_t)(r + 2) * 1024], a2);
        a3 = fmaf(hs[r + 3], w[(size_t)(r + 3) * 1024], a3);
    }
    ps[t] = (a0 + a1) + (a2 + a3);
    __syncthreads();
    if (t < 16) {
        float s = 0;
        #pragma unroll
        for (int k = 0; k < 16; ++k) s += ps[t + 16 * k];
        vr16[t] = s + b2[512 + c0 + t];
    }
    __syncthreads();
    // partial outer product: 16 MACs/thread, Wv rows c0..c0+15, coalesced in t
    const float* wv = Wv + (size_t)c0 * 256 + t;
    float acc0 = 0, acc1 = 0;
    #pragma unroll
    for (int k = 0; k < 16; k += 2) {
        acc0 = fmaf(vr16[k],     wv[(k + 0) * 256], acc0);
        acc1 = fmaf(vr16[k + 1], wv[(k + 1) * 256], acc1);
    }
    vp_part[(size_t)blockIdx.x * 256 + t] = acc0 + acc1;
}

// K3: block (b,c): vp[t] = sum_{p<32} vp_part[b*32+p][t] + bv[t];
// o9 = 9*(dot(vp, Wo[:,c]) + bo[c]); broadcast over 4096 slots. grid 1024.
__global__ __launch_bounds__(256) void k_out3(const float* __restrict__ vp_part,
                                              const float* __restrict__ bv,
                                              const float* __restrict__ Wo,
                                              const float* __restrict__ bo,
                                              float4* __restrict__ out) {
    int b = blockIdx.x >> 8, c = blockIdx.x & 255, t = threadIdx.x;
    __shared__ float red[256];
    const float* vpp = vp_part + (size_t)b * 32 * 256 + t;
    float s0 = 0, s1 = 0, s2 = 0, s3 = 0;
    #pragma unroll
    for (int p = 0; p < 32; p += 4) {
        s0 += vpp[(p + 0) * 256];
        s1 += vpp[(p + 1) * 256];
        s2 += vpp[(p + 2) * 256];
        s3 += vpp[(p + 3) * 256];
    }
    float vpv = ((s0 + s1) + (s2 + s3)) + bv[t];
    red[t] = vpv * Wo[(size_t)t * 256 + c];
    __syncthreads();
    if (t < 64) {
        float s = (red[t] + red[t + 64]) + (red[t + 128] + red[t + 192]);
        s += __shfl_down(s, 32);
        s += __shfl_down(s, 16);
        s += __shfl_down(s, 8);
        s += __shfl_down(s, 4);
        s += __shfl_down(s, 2);
        s += __shfl_down(s, 1);
        if (t == 0) red[0] = 9.0f * (s + bo[c]);
    }
    __syncthreads();
    float v = red[0];
    float4 vv = make_float4(v, v, v, v);
    float4* p = out + (size_t)blockIdx.x * 1024;
    p[t]       = vv;
    p[t + 256] = vv;
    p[t + 512] = vv;
    p[t + 768] = vv;
}

// ---------------- fallback (proven round-2 kernels, 28KB ws) ----------------
__global__ __launch_bounds__(256) void k_vraw(const float* __restrict__ hidden,
                                              const float* __restrict__ W2,
                                              const float* __restrict__ b2,
                                              float* __restrict__ v_raw) {
    int b  = blockIdx.x >> 5;
    int c0 = (blockIdx.x & 31) * 16;
    int t  = threadIdx.x;
    int col = c0 + (t & 15);
    int kc  = t >> 4;
    __shared__ float h_s[1024];
    __shared__ float ps[256];
    h_s[t]       = hidden[b * 1024 + t];
    h_s[t + 256] = hidden[b * 1024 + t + 256];
    h_s[t + 512] = hidden[b * 1024 + t + 512];
    h_s[t + 768] = hidden[b * 1024 + t + 768];
    __syncthreads();
    const float* w  = W2 + (size_t)(kc * 64) * 1024 + 512 + col;
    const float* hs = h_s + kc * 64;
    float a0 = 0, a1 = 0, a2 = 0, a3 = 0;
    for (int r = 0; r < 64; r += 4) {
        a0 = fmaf(hs[r + 0], w[(size_t)(r + 0) * 1024], a0);
        a1 = fmaf(hs[r + 1], w[(size_t)(r + 1) * 1024], a1);
        a2 = fmaf(hs[r + 2], w[(size_t)(r + 2) * 1024], a2);
        a3 = fmaf(hs[r + 3], w[(size_t)(r + 3) * 1024], a3);
    }
    ps[t] = (a0 + a1) + (a2 + a3);
    __syncthreads();
    if (t < 16) {
        float s = 0;
        #pragma unroll
        for (int k = 0; k < 16; ++k) s += ps[t + 16 * k];
        v_raw[b * 512 + c0 + t] = s + b2[512 + c0 + t];
    }
}

__global__ __launch_bounds__(256) void k_vp(const float* __restrict__ v_raw,
                                            const float* __restrict__ Wv,
                                            const float* __restrict__ bv,
                                            float* __restrict__ vp) {
    int b  = blockIdx.x >> 3;
    int d0 = (blockIdx.x & 7) * 32;
    int t  = threadIdx.x;
    int col = d0 + (t & 31), kc = t >> 5;
    __shared__ float v_s[512];
    __shared__ float ps[256];
    v_s[t]       = v_raw[b * 512 + t];
    v_s[t + 256] = v_raw[b * 512 + t + 256];
    __syncthreads();
    const float* w  = Wv + (size_t)(kc * 64) * 256 + col;
    const float* vs = v_s + kc * 64;
    float a0 = 0, a1 = 0, a2 = 0, a3 = 0;
    for (int r = 0; r < 64; r += 4) {
        a0 = fmaf(vs[r + 0], w[(r + 0) * 256], a0);
        a1 = fmaf(vs[r + 1], w[(r + 1) * 256], a1);
        a2 = fmaf(vs[r + 2], w[(r + 2) * 256], a2);
        a3 = fmaf(vs[r + 3], w[(r + 3) * 256], a3);
    }
    ps[t] = (a0 + a1) + (a2 + a3);
    __syncthreads();
    if (t < 32) {
        float s = 0;
        #pragma unroll
        for (int k = 0; k < 8; ++k) s += ps[t + 32 * k];
        vp[b * 256 + d0 + t] = s + bv[d0 + t];
    }
}

__global__ __launch_bounds__(256) void k_out(const float* __restrict__ vp,
                                             const float* __restrict__ Wo,
                                             const float* __restrict__ bo,
                                             float4* __restrict__ out) {
    int b = blockIdx.x >> 8, c = blockIdx.x & 255, t = threadIdx.x;
    __shared__ float red[256];
    red[t] = vp[b * 256 + t] * Wo[(size_t)t * 256 + c];
    __syncthreads();
    if (t < 64) {
        float s = (red[t] + red[t + 64]) + (red[t + 128] + red[t + 192]);
        s += __shfl_down(s, 32);
        s += __shfl_down(s, 16);
        s += __shfl_down(s, 8);
        s += __shfl_down(s, 4);
        s += __shfl_down(s, 2);
        s += __shfl_down(s, 1);
        if (t == 0) red[0] = 9.0f * (s + bo[c]);
    }
    __syncthreads();
    float v = red[0];
    float4 vv = make_float4(v, v, v, v);
    float4* p = out + (size_t)blockIdx.x * 1024;
    p[t]       = vv;
    p[t + 256] = vv;
    p[t + 512] = vv;
    p[t + 768] = vv;
}

extern "C" void kernel_launch(void* const* d_in, const int* in_sizes, int n_in,
                              void* d_out, int out_size, void* d_ws, size_t ws_size,
                              hipStream_t stream) {
    // 0:x 1:y 2:Wp 3:bp 4:W1 5:b1 6:W2 7:b2 8:Wq 9:bq 10:Wk 11:bk 12:Wv 13:bv 14:Wo 15:bo
    const float* y  = (const float*)d_in[1];
    const float* W1 = (const float*)d_in[4];
    const float* b1 = (const float*)d_in[5];
    const float* W2 = (const float*)d_in[6];
    const float* b2 = (const float*)d_in[7];
    const float* Wv = (const float*)d_in[12];
    const float* bv = (const float*)d_in[13];
    const float* Wo = (const float*)d_in[14];
    const float* bo = (const float*)d_in[15];

    float* ws      = (float*)d_ws;
    float* hidden  = ws;          // 4096 floats
    float* vp_part = ws + 4096;   // 128 blocks x 256 = 32768 floats
    const size_t need = (size_t)(4096 + 32768) * 4;   // 147KB

    if (ws_size >= need) {
        k_hidden     <<<64,   256, 0, stream>>>(y, W1, b1, hidden);
        k_vraw_vppart<<<128,  256, 0, stream>>>(hidden, W2, b2, Wv, vp_part);
        k_out3       <<<1024, 256, 0, stream>>>(vp_part, bv, Wo, bo, (float4*)d_out);
    } else {
        float* v_raw = ws + 4096;  // 2048
        float* vp    = ws + 6144;  // 1024
        k_hidden<<<64,   256, 0, stream>>>(y, W1, b1, hidden);
        k_vraw  <<<128,  256, 0, stream>>>(hidden, W2, b2, v_raw);
        k_vp    <<<32,   256, 0, stream>>>(v_raw, Wv, bv, vp);
        k_out   <<<1024, 256, 0, stream>>>(vp, Wo, bo, (float4*)d_out);
    }
}